// Round 7
// baseline (23889.966 us; speedup 1.0000x reference)
//
#include <hip/hip_runtime.h>

typedef __attribute__((ext_vector_type(8))) short short8;
typedef __attribute__((ext_vector_type(4))) float f32x4;
typedef __attribute__((ext_vector_type(4))) unsigned short ushort4_t;
typedef __attribute__((ext_vector_type(4))) float float4_t;
typedef __attribute__((ext_vector_type(4))) unsigned int uintx4;
typedef _Float16 half2_t __attribute__((ext_vector_type(2)));

#define DEVI static __device__ __forceinline__

DEVI unsigned short f2b(float f){
    unsigned int u = __float_as_uint(f);
    u += 0x7fffu + ((u >> 16) & 1u);
    return (unsigned short)(u >> 16);
}
DEVI float b2f(unsigned short h){ return __uint_as_float(((unsigned int)h) << 16); }

DEVI float sigm(float x){
    float e = __expf(-x);
    return __builtin_amdgcn_rcpf(1.f + e);
}
DEVI float tanh_(float x){
    float e = __expf(2.f * x);              // overflow -> inf -> rcp -> 0 -> tanh=1 (graceful)
    return 1.f - 2.f * __builtin_amdgcn_rcpf(1.f + e);
}

// v_dot2_f32_f16: full f32 accumulate, fp16 products
DEVI float dot2h(unsigned int a, unsigned int b, float acc){
    half2_t ah = __builtin_bit_cast(half2_t, a);
    half2_t bh = __builtin_bit_cast(half2_t, b);
    return __builtin_amdgcn_fdot2(ah, bh, acc, false);
}

// ---------------------------------------------------------------------------
// Weight cast f32 -> bf16 (GEMM weights) or fp16 (W_hh, scan-only) into wbuf
// ---------------------------------------------------------------------------
struct CastArgs { const float* s[10]; };

__global__ __launch_bounds__(256, 4) void cast_w(CastArgs ca, unsigned short* __restrict__ wbuf){
    const int off[10] = {0,196608,393216,589824,786432,1179648,1376256,1769472,1966080,2097152};
    const int cnt[10] = {196608,196608,196608,196608,393216,196608,393216,196608,131072,131072};
    int seg = blockIdx.y;
    bool f16 = (seg == 1) || (seg == 3) || (seg == 5) || (seg == 7);   // W_hh segs
    const float* s = ca.s[seg];
    unsigned short* d = wbuf + off[seg];
    int n = cnt[seg];
    for (int i = (blockIdx.x * 256 + threadIdx.x) * 4; i < n; i += 192 * 256 * 4){
        float4_t v = *(const float4_t*)&s[i];
        ushort4_t o;
        if (f16){
            o[0] = __builtin_bit_cast(unsigned short, (_Float16)v[0]);
            o[1] = __builtin_bit_cast(unsigned short, (_Float16)v[1]);
            o[2] = __builtin_bit_cast(unsigned short, (_Float16)v[2]);
            o[3] = __builtin_bit_cast(unsigned short, (_Float16)v[3]);
        } else {
            o[0] = f2b(v[0]); o[1] = f2b(v[1]); o[2] = f2b(v[2]); o[3] = f2b(v[3]);
        }
        *(ushort4_t*)&d[i] = o;
    }
}

// ---------------------------------------------------------------------------
// x (B,C,L) f32  ->  xT (B, L, C) bf16
// ---------------------------------------------------------------------------
__global__ __launch_bounds__(256, 4) void transpose_x(const float* __restrict__ x, unsigned short* __restrict__ xT){
    __shared__ float tile[32][33];
    int t0 = blockIdx.x * 32, c0 = blockIdx.y * 32, b = blockIdx.z;
    int tid = threadIdx.x;
    int r  = tid >> 3;          // 0..31
    int jc = (tid & 7) * 4;     // 0..28
    float4_t v = *(const float4_t*)&x[(size_t)b * 524288 + (size_t)(c0 + r) * 2048 + t0 + jc];
    tile[r][jc + 0] = v[0]; tile[r][jc + 1] = v[1]; tile[r][jc + 2] = v[2]; tile[r][jc + 3] = v[3];
    __syncthreads();
    int rt = tid >> 3;          // t row 0..31
    int cc = (tid & 7) * 4;     // c 0..28
    ushort4_t o;
    o[0] = f2b(tile[cc + 0][rt]);
    o[1] = f2b(tile[cc + 1][rt]);
    o[2] = f2b(tile[cc + 2][rt]);
    o[3] = f2b(tile[cc + 3][rt]);
    *(ushort4_t*)&xT[((size_t)b * 2048 + t0 + rt) * 256 + c0 + cc] = o;
}

// ---------------------------------------------------------------------------
// GEMM: C[M][N] = A[M][K] @ Bw[N][K]^T + bias1 (+bias2 if col<bias2_lim), bf16 out
// 64x64 tile, 4 waves, MFMA 16x16x32 bf16
// ---------------------------------------------------------------------------
template<int RELU>
__global__ __launch_bounds__(256, 4) void gemm64(
    const unsigned short* __restrict__ A, const unsigned short* __restrict__ Bw,
    const float* __restrict__ bias1, const float* __restrict__ bias2, int bias2_lim,
    unsigned short* __restrict__ Cout, int K, int N)
{
    __shared__ unsigned short As[64][72];
    __shared__ unsigned short Bs[64][72];
    int m0 = blockIdx.x * 64, n0 = blockIdx.y * 64;
    int tid = threadIdx.x, lane = tid & 63, w = tid >> 6;
    int l15 = lane & 15, kq = lane >> 4;
    int lr = tid >> 2, lc = (tid & 3) * 16;
    f32x4 acc[4];
#pragma unroll
    for (int n = 0; n < 4; ++n) acc[n] = (f32x4){0.f, 0.f, 0.f, 0.f};

    for (int kt = 0; kt < K; kt += 64){
        short8 a0 = *(const short8*)&A[(size_t)(m0 + lr) * K + kt + lc];
        short8 a1 = *(const short8*)&A[(size_t)(m0 + lr) * K + kt + lc + 8];
        short8 b0 = *(const short8*)&Bw[(size_t)(n0 + lr) * K + kt + lc];
        short8 b1 = *(const short8*)&Bw[(size_t)(n0 + lr) * K + kt + lc + 8];
        __syncthreads();
        *(short8*)&As[lr][lc]     = a0;
        *(short8*)&As[lr][lc + 8] = a1;
        *(short8*)&Bs[lr][lc]     = b0;
        *(short8*)&Bs[lr][lc + 8] = b1;
        __syncthreads();
#pragma unroll
        for (int kc = 0; kc < 2; ++kc){
            short8 af = *(const short8*)&As[w * 16 + l15][kc * 32 + kq * 8];
#pragma unroll
            for (int n = 0; n < 4; ++n){
                short8 bfv = *(const short8*)&Bs[n * 16 + l15][kc * 32 + kq * 8];
                acc[n] = __builtin_amdgcn_mfma_f32_16x16x32_bf16(af, bfv, acc[n], 0, 0, 0);
            }
        }
    }
#pragma unroll
    for (int n = 0; n < 4; ++n){
        int col = n0 + n * 16 + l15;
        float bs = bias1 ? bias1[col] : 0.f;
        if (bias2 && col < bias2_lim) bs += bias2[col];
#pragma unroll
        for (int r = 0; r < 4; ++r){
            int row = m0 + w * 16 + kq * 4 + r;
            float v = acc[n][r] + bs;
            if (RELU) v = fmaxf(v, 0.f);
            Cout[(size_t)row * N + col] = f2b(v);
        }
    }
}

// ---------------------------------------------------------------------------
// Final FFN GEMM with f32 output written TRANSPOSED to (B,C,L):
// out[b][col][t] = A[row=b*2048+t] @ w2^T + b2
// ---------------------------------------------------------------------------
__global__ __launch_bounds__(256, 4) void gemm64_tr(
    const unsigned short* __restrict__ A, const unsigned short* __restrict__ Bw,
    const float* __restrict__ bias, float* __restrict__ Out, int K, int N)
{
    __shared__ unsigned short As[64][72];
    __shared__ unsigned short Bs[64][72];
    int m0 = blockIdx.x * 64, n0 = blockIdx.y * 64;
    int tid = threadIdx.x, lane = tid & 63, w = tid >> 6;
    int l15 = lane & 15, kq = lane >> 4;
    int lr = tid >> 2, lc = (tid & 3) * 16;
    f32x4 acc[4];
#pragma unroll
    for (int n = 0; n < 4; ++n) acc[n] = (f32x4){0.f, 0.f, 0.f, 0.f};

    for (int kt = 0; kt < K; kt += 64){
        short8 a0 = *(const short8*)&A[(size_t)(m0 + lr) * K + kt + lc];
        short8 a1 = *(const short8*)&A[(size_t)(m0 + lr) * K + kt + lc + 8];
        short8 b0 = *(const short8*)&Bw[(size_t)(n0 + lr) * K + kt + lc];
        short8 b1 = *(const short8*)&Bw[(size_t)(n0 + lr) * K + kt + lc + 8];
        __syncthreads();
        *(short8*)&As[lr][lc]     = a0;
        *(short8*)&As[lr][lc + 8] = a1;
        *(short8*)&Bs[lr][lc]     = b0;
        *(short8*)&Bs[lr][lc + 8] = b1;
        __syncthreads();
#pragma unroll
        for (int kc = 0; kc < 2; ++kc){
            short8 af = *(const short8*)&As[w * 16 + l15][kc * 32 + kq * 8];
#pragma unroll
            for (int n = 0; n < 4; ++n){
                short8 bfv = *(const short8*)&Bs[n * 16 + l15][kc * 32 + kq * 8];
                acc[n] = __builtin_amdgcn_mfma_f32_16x16x32_bf16(af, bfv, acc[n], 0, 0, 0);
            }
        }
    }
    int m_base = m0 + w * 16 + kq * 4;
    int bidx = m_base >> 11;
    int t0 = m_base & 2047;
#pragma unroll
    for (int n = 0; n < 4; ++n){
        int col = n0 + n * 16 + l15;
        float bs = bias[col];
        float4_t o = (float4_t){acc[n][0] + bs, acc[n][1] + bs, acc[n][2] + bs, acc[n][3] + bs};
        *(float4_t*)&Out[(size_t)bidx * 524288 + (size_t)col * 2048 + t0] = o;
    }
}

// ---------------------------------------------------------------------------
// GRU scan via v_dot2_f32_f16, split-residency weights:
//   K[0,128):  64 packed pairs pinned in VGPRs (fits comfortably in the
//              170-VGPR budget at 3 waves/SIMD — past rounds showed the
//              allocator bails when pinned demand >= ~93% of budget)
//   K[128,256): streamed from L2 each step in two 32-dword chunks that
//              reuse the same 8 named uintx4 registers (32 VGPRs in flight).
//              Chunk0 issued at the top of the step; its latency hides under
//              the 64-pair resident dot. Address laundered via asm("+s") per
//              iteration so loads can't be hoisted into loop-carried regs.
// 768 thr = 12 waves (3/SIMD). Lane owns W_hh row tid (gate g=tid>>8, col
// c=tid&255). h fp16 in LDS (uniform broadcast reads). 2 barriers/step.
// ---------------------------------------------------------------------------
__global__ __launch_bounds__(768, 3) void gru_scan_dot(
    const unsigned short* __restrict__ gi,
    const unsigned short* __restrict__ whh_f, const unsigned short* __restrict__ whh_b,
    const float* __restrict__ bhh_f, const float* __restrict__ bhh_b,
    unsigned short* __restrict__ outp, int out_stride, size_t out_dir_off)
{
    const int T = 2048;
    int b = blockIdx.x & 15, dir = blockIdx.x >> 4;
    const unsigned short* giP = gi + ((size_t)(dir * 16 + b)) * T * 768;
    const unsigned short* wP  = dir ? whh_b : whh_f;    // fp16 storage
    const float* bhP          = dir ? bhh_b : bhh_f;
    unsigned short* oP        = outp + out_dir_off * (size_t)dir;

    int tid = threadIdx.x;      // 0..767
    int g = tid >> 8;           // 0:r 1:z 2:n  (wave-uniform)
    int c = tid & 255;

    // resident half: W_hh row `tid`, elems [0,128) = 64 packed fp16 pairs
    unsigned int wres[64];
    {
        const uintx4* wrow = (const uintx4*)(wP + (size_t)tid * 256);
#pragma unroll
        for (int i = 0; i < 16; ++i){
            uintx4 v = wrow[i];
            wres[i * 4 + 0] = v[0];
            wres[i * 4 + 1] = v[1];
            wres[i * 4 + 2] = v[2];
            wres[i * 4 + 3] = v[3];
        }
    }
#pragma unroll
    for (int i = 0; i < 64; ++i) asm volatile("" : "+v"(wres[i]));

    float bhn = (g == 2) ? bhP[512 + c] : 0.f;

    __shared__ unsigned int hlds[2][128];   // 256 fp16 h, double-buffered
    __shared__ float gbuf[768];             // gate exchange

    if (tid < 128) hlds[0][tid] = 0;

    int tt0 = dir ? (T - 1) : 0;
    int tstep = dir ? -1 : 1;

    // gi for t=0
    unsigned short gcur = giP[(size_t)tt0 * 768 + tid];
    unsigned short gncur = 0;
    if (tid < 256) gncur = giP[(size_t)tt0 * 768 + 512 + c];
    __syncthreads();

    float hold = 0.f;
    int cur = 0, tt = tt0;
#pragma clang loop unroll(disable)
    for (int t = 0; t < T; ++t){
        // launder streamed-weight base so loads are re-issued every step
        const unsigned short* wSt = wP;
        asm volatile("" : "+s"(wSt));
        const uintx4* wrow2 = (const uintx4*)(wSt + (size_t)tid * 256);

        // issue chunk0 (elems [128,192) = wrow2[16..23])
        uintx4 q0 = wrow2[16], q1 = wrow2[17], q2 = wrow2[18], q3 = wrow2[19];
        uintx4 q4 = wrow2[20], q5 = wrow2[21], q6 = wrow2[22], q7 = wrow2[23];

        int tn = (t + 1 < T) ? (tt + tstep) : tt;
        // prefetch next step's gi (hidden under dot phase)
        unsigned short gnx = giP[(size_t)tn * 768 + tid];
        unsigned short gnnx = 0;
        if (tid < 256) gnnx = giP[(size_t)tn * 768 + 512 + c];

        const uintx4* hlds4 = (const uintx4*)hlds[cur];

        // resident dot: K elems [0,128)
        float a0 = 0.f, a1 = 0.f, a2 = 0.f, a3 = 0.f;
#pragma unroll
        for (int kk = 0; kk < 16; ++kk){
            uintx4 hv = hlds4[kk];
            a0 = dot2h(wres[kk * 4 + 0], hv[0], a0);
            a1 = dot2h(wres[kk * 4 + 1], hv[1], a1);
            a2 = dot2h(wres[kk * 4 + 2], hv[2], a2);
            a3 = dot2h(wres[kk * 4 + 3], hv[3], a3);
        }

        // consume chunk0 (h dwords [64,96) = hlds4[16..23])
        {
            uintx4 hv;
            hv = hlds4[16]; a0 = dot2h(q0[0], hv[0], a0); a1 = dot2h(q0[1], hv[1], a1); a2 = dot2h(q0[2], hv[2], a2); a3 = dot2h(q0[3], hv[3], a3);
            hv = hlds4[17]; a0 = dot2h(q1[0], hv[0], a0); a1 = dot2h(q1[1], hv[1], a1); a2 = dot2h(q1[2], hv[2], a2); a3 = dot2h(q1[3], hv[3], a3);
            hv = hlds4[18]; a0 = dot2h(q2[0], hv[0], a0); a1 = dot2h(q2[1], hv[1], a1); a2 = dot2h(q2[2], hv[2], a2); a3 = dot2h(q2[3], hv[3], a3);
            hv = hlds4[19]; a0 = dot2h(q3[0], hv[0], a0); a1 = dot2h(q3[1], hv[1], a1); a2 = dot2h(q3[2], hv[2], a2); a3 = dot2h(q3[3], hv[3], a3);
            hv = hlds4[20]; a0 = dot2h(q4[0], hv[0], a0); a1 = dot2h(q4[1], hv[1], a1); a2 = dot2h(q4[2], hv[2], a2); a3 = dot2h(q4[3], hv[3], a3);
            hv = hlds4[21]; a0 = dot2h(q5[0], hv[0], a0); a1 = dot2h(q5[1], hv[1], a1); a2 = dot2h(q5[2], hv[2], a2); a3 = dot2h(q5[3], hv[3], a3);
            hv = hlds4[22]; a0 = dot2h(q6[0], hv[0], a0); a1 = dot2h(q6[1], hv[1], a1); a2 = dot2h(q6[2], hv[2], a2); a3 = dot2h(q6[3], hv[3], a3);
            hv = hlds4[23]; a0 = dot2h(q7[0], hv[0], a0); a1 = dot2h(q7[1], hv[1], a1); a2 = dot2h(q7[2], hv[2], a2); a3 = dot2h(q7[3], hv[3], a3);
        }

        // issue chunk1 into the same q regs (elems [192,256) = wrow2[24..31])
        q0 = wrow2[24]; q1 = wrow2[25]; q2 = wrow2[26]; q3 = wrow2[27];
        q4 = wrow2[28]; q5 = wrow2[29]; q6 = wrow2[30]; q7 = wrow2[31];

        // consume chunk1 (h dwords [96,128) = hlds4[24..31])
        {
            uintx4 hv;
            hv = hlds4[24]; a0 = dot2h(q0[0], hv[0], a0); a1 = dot2h(q0[1], hv[1], a1); a2 = dot2h(q0[2], hv[2], a2); a3 = dot2h(q0[3], hv[3], a3);
            hv = hlds4[25]; a0 = dot2h(q1[0], hv[0], a0); a1 = dot2h(q1[1], hv[1], a1); a2 = dot2h(q1[2], hv[2], a2); a3 = dot2h(q1[3], hv[3], a3);
            hv = hlds4[26]; a0 = dot2h(q2[0], hv[0], a0); a1 = dot2h(q2[1], hv[1], a1); a2 = dot2h(q2[2], hv[2], a2); a3 = dot2h(q2[3], hv[3], a3);
            hv = hlds4[27]; a0 = dot2h(q3[0], hv[0], a0); a1 = dot2h(q3[1], hv[1], a1); a2 = dot2h(q3[2], hv[2], a2); a3 = dot2h(q3[3], hv[3], a3);
            hv = hlds4[28]; a0 = dot2h(q4[0], hv[0], a0); a1 = dot2h(q4[1], hv[1], a1); a2 = dot2h(q4[2], hv[2], a2); a3 = dot2h(q4[3], hv[3], a3);
            hv = hlds4[29]; a0 = dot2h(q5[0], hv[0], a0); a1 = dot2h(q5[1], hv[1], a1); a2 = dot2h(q5[2], hv[2], a2); a3 = dot2h(q5[3], hv[3], a3);
            hv = hlds4[30]; a0 = dot2h(q6[0], hv[0], a0); a1 = dot2h(q6[1], hv[1], a1); a2 = dot2h(q6[2], hv[2], a2); a3 = dot2h(q6[3], hv[3], a3);
            hv = hlds4[31]; a0 = dot2h(q7[0], hv[0], a0); a1 = dot2h(q7[1], hv[1], a1); a2 = dot2h(q7[2], hv[2], a2); a3 = dot2h(q7[3], hv[3], a3);
        }

        float a = (a0 + a1) + (a2 + a3);

        float val;
        if (g < 2) val = sigm(b2f(gcur) + a);   // r or z (sigmoid now)
        else       val = a + bhn;               // n partial (needs r later)
        gbuf[tid] = val;
        __syncthreads();                        // bar1: gates published

        int nxt = cur ^ 1;
        if (tid < 256){
            float rr = val;                     // own r (this lane computed it)
            float zz = gbuf[256 + c];
            float s  = gbuf[512 + c];
            float nn = tanh_(b2f(gncur) + rr * s);
            float hv = nn + zz * (hold - nn);
            hold = hv;
            ((unsigned short*)hlds[nxt])[c] = __builtin_bit_cast(unsigned short, (_Float16)hv);
            oP[(size_t)(b * T + tt) * out_stride + c] = f2b(hv);
        }
        __syncthreads();                        // bar2: h visible, gbuf free
        gcur = gnx; gncur = gnnx;
        tt += tstep;
        cur = nxt;
    }
}

// ---------------------------------------------------------------------------
// sum(fwd,bwd) + LayerNorm -> bf16 rows
// ---------------------------------------------------------------------------
__global__ __launch_bounds__(256, 4) void sum_ln(
    const unsigned short* __restrict__ h1, const float* __restrict__ g,
    const float* __restrict__ bb, unsigned short* __restrict__ vn)
{
    int row = blockIdx.x * 4 + (threadIdx.x >> 6);
    int lane = threadIdx.x & 63;
    ushort4_t fa = *(const ushort4_t*)&h1[(size_t)row * 256 + lane * 4];
    ushort4_t ba = *(const ushort4_t*)&h1[8388608 + (size_t)row * 256 + lane * 4];
    float v[4]; float s = 0.f, q = 0.f;
#pragma unroll
    for (int k = 0; k < 4; ++k){
        v[k] = b2f(fa[k]) + b2f(ba[k]);
        s += v[k]; q += v[k] * v[k];
    }
#pragma unroll
    for (int o = 32; o; o >>= 1){
        s += __shfl_xor(s, o);
        q += __shfl_xor(q, o);
    }
    float mu = s * (1.f / 256.f);
    float var = q * (1.f / 256.f) - mu * mu;
    float rs = rsqrtf(var + 1e-5f);
    float4_t gg = *(const float4_t*)&g[lane * 4];
    float4_t bv = *(const float4_t*)&bb[lane * 4];
    ushort4_t o4;
#pragma unroll
    for (int k = 0; k < 4; ++k) o4[k] = f2b((v[k] - mu) * rs * gg[k] + bv[k]);
    *(ushort4_t*)&vn[(size_t)row * 256 + lane * 4] = o4;
}

// ---------------------------------------------------------------------------
extern "C" void kernel_launch(void* const* d_in, const int* in_sizes, int n_in,
                              void* d_out, int out_size, void* d_ws, size_t ws_size,
                              hipStream_t stream)
{
    (void)in_sizes; (void)n_in; (void)out_size; (void)ws_size;
    const float* x = (const float*)d_in[0];

    char* ws = (char*)d_ws;
    unsigned short* xT   = (unsigned short*)(ws);                 // 16 MB   (later reused as vn)
    unsigned short* giA  = (unsigned short*)(ws + 16777216);      // 100.7MB (gi0 -> gi1 -> hid)
    unsigned short* h0   = (unsigned short*)(ws + 117440512);     // 33.6 MB (h0out -> h1out)
    unsigned short* wbuf = (unsigned short*)(ws + 150994944);     // 4.5 MB weights (bf16 / fp16)
    float* out = (float*)d_out;

    // 1) cast weights (W_hh segs -> fp16 for the dot2 scan; others bf16)
    CastArgs ca;
    ca.s[0] = (const float*)d_in[1];   // w_ih0f
    ca.s[1] = (const float*)d_in[2];   // w_hh0f (fp16)
    ca.s[2] = (const float*)d_in[5];   // w_ih0b
    ca.s[3] = (const float*)d_in[6];   // w_hh0b (fp16)
    ca.s[4] = (const float*)d_in[9];   // w_ih1f
    ca.s[5] = (const float*)d_in[10];  // w_hh1f (fp16)
    ca.s[6] = (const float*)d_in[13];  // w_ih1b
    ca.s[7] = (const float*)d_in[14];  // w_hh1b (fp16)
    ca.s[8] = (const float*)d_in[19];  // w1
    ca.s[9] = (const float*)d_in[21];  // w2
    cast_w<<<dim3(192, 10), 256, 0, stream>>>(ca, wbuf);

    // 2) transpose x -> xT bf16
    transpose_x<<<dim3(64, 8, 16), 256, 0, stream>>>(x, xT);

    // 3) layer-0 input gates: gi0[dir] = xT @ w_ih0d^T + b_ih0d + b_hh0d(r,z)
    gemm64<0><<<dim3(512, 12), 256, 0, stream>>>(xT, wbuf + 0,
        (const float*)d_in[3], (const float*)d_in[4], 512, giA, 256, 768);
    gemm64<0><<<dim3(512, 12), 256, 0, stream>>>(xT, wbuf + 393216,
        (const float*)d_in[7], (const float*)d_in[8], 512, giA + (size_t)25165824, 256, 768);

    // 4) layer-0 scan -> h0 [32768][512] (fwd cols 0-255, bwd 256-511)
    gru_scan_dot<<<32, 768, 0, stream>>>(giA, wbuf + 196608, wbuf + 589824,
        (const float*)d_in[4], (const float*)d_in[8], h0, 512, (size_t)256);

    // 5) layer-1 input gates from h0 (K=512)
    gemm64<0><<<dim3(512, 12), 256, 0, stream>>>(h0, wbuf + 786432,
        (const float*)d_in[11], (const float*)d_in[12], 512, giA, 512, 768);
    gemm64<0><<<dim3(512, 12), 256, 0, stream>>>(h0, wbuf + 1376256,
        (const float*)d_in[15], (const float*)d_in[16], 512, giA + (size_t)25165824, 512, 768);

    // 6) layer-1 scan -> h0 reused as h1out [2][32768][256]
    gru_scan_dot<<<32, 768, 0, stream>>>(giA, wbuf + 1179648, wbuf + 1769472,
        (const float*)d_in[12], (const float*)d_in[16], h0, 256, (size_t)8388608);

    // 7) sum dirs + LayerNorm -> vn (reuse xT)
    sum_ln<<<8192, 256, 0, stream>>>(h0, (const float*)d_in[17], (const float*)d_in[18], xT);

    // 8) FFN1: relu(vn @ w1^T + b1) -> hid (reuse giA)
    gemm64<1><<<dim3(512, 8), 256, 0, stream>>>(xT, wbuf + 1966080,
        (const float*)d_in[20], nullptr, 0, giA, 256, 512);

    // 9) FFN2: hid @ w2^T + b2 -> d_out f32, transposed to (B,C,L)
    gemm64_tr<<<dim3(512, 4), 256, 0, stream>>>(giA, wbuf + 2097152,
        (const float*)d_in[22], out, 512, 256);
}

// Round 9
// 6716.507 us; speedup vs baseline: 3.5569x; 3.5569x over previous
//
#include <hip/hip_runtime.h>

typedef __attribute__((ext_vector_type(8))) short short8;
typedef __attribute__((ext_vector_type(4))) float f32x4;
typedef __attribute__((ext_vector_type(4))) unsigned short ushort4_t;
typedef __attribute__((ext_vector_type(4))) float float4_t;
typedef __attribute__((ext_vector_type(4))) unsigned int uintx4;
typedef _Float16 half2_t __attribute__((ext_vector_type(2)));

#define DEVI static __device__ __forceinline__

DEVI unsigned short f2b(float f){
    unsigned int u = __float_as_uint(f);
    u += 0x7fffu + ((u >> 16) & 1u);
    return (unsigned short)(u >> 16);
}
DEVI float b2f(unsigned short h){ return __uint_as_float(((unsigned int)h) << 16); }

DEVI float sigm(float x){
    float e = __expf(-x);
    return __builtin_amdgcn_rcpf(1.f + e);
}
DEVI float tanh_(float x){
    float e = __expf(2.f * x);              // overflow -> inf -> rcp -> 0 -> tanh=1 (graceful)
    return 1.f - 2.f * __builtin_amdgcn_rcpf(1.f + e);
}

// v_dot2_f32_f16: full f32 accumulate, fp16 products
DEVI float dot2h(unsigned int a, unsigned int b, float acc){
    half2_t ah = __builtin_bit_cast(half2_t, a);
    half2_t bh = __builtin_bit_cast(half2_t, b);
    return __builtin_amdgcn_fdot2(ah, bh, acc, false);
}

// ---------------------------------------------------------------------------
// Weight cast f32 -> bf16 (GEMM weights) or fp16 (W_hh, scan-only) into wbuf
// ---------------------------------------------------------------------------
struct CastArgs { const float* s[10]; };

__global__ __launch_bounds__(256, 4) void cast_w(CastArgs ca, unsigned short* __restrict__ wbuf){
    const int off[10] = {0,196608,393216,589824,786432,1179648,1376256,1769472,1966080,2097152};
    const int cnt[10] = {196608,196608,196608,196608,393216,196608,393216,196608,131072,131072};
    int seg = blockIdx.y;
    bool f16 = (seg == 1) || (seg == 3) || (seg == 5) || (seg == 7);   // W_hh segs
    const float* s = ca.s[seg];
    unsigned short* d = wbuf + off[seg];
    int n = cnt[seg];
    for (int i = (blockIdx.x * 256 + threadIdx.x) * 4; i < n; i += 192 * 256 * 4){
        float4_t v = *(const float4_t*)&s[i];
        ushort4_t o;
        if (f16){
            o[0] = __builtin_bit_cast(unsigned short, (_Float16)v[0]);
            o[1] = __builtin_bit_cast(unsigned short, (_Float16)v[1]);
            o[2] = __builtin_bit_cast(unsigned short, (_Float16)v[2]);
            o[3] = __builtin_bit_cast(unsigned short, (_Float16)v[3]);
        } else {
            o[0] = f2b(v[0]); o[1] = f2b(v[1]); o[2] = f2b(v[2]); o[3] = f2b(v[3]);
        }
        *(ushort4_t*)&d[i] = o;
    }
}

// ---------------------------------------------------------------------------
// x (B,C,L) f32  ->  xT (B, L, C) bf16
// ---------------------------------------------------------------------------
__global__ __launch_bounds__(256, 4) void transpose_x(const float* __restrict__ x, unsigned short* __restrict__ xT){
    __shared__ float tile[32][33];
    int t0 = blockIdx.x * 32, c0 = blockIdx.y * 32, b = blockIdx.z;
    int tid = threadIdx.x;
    int r  = tid >> 3;          // 0..31
    int jc = (tid & 7) * 4;     // 0..28
    float4_t v = *(const float4_t*)&x[(size_t)b * 524288 + (size_t)(c0 + r) * 2048 + t0 + jc];
    tile[r][jc + 0] = v[0]; tile[r][jc + 1] = v[1]; tile[r][jc + 2] = v[2]; tile[r][jc + 3] = v[3];
    __syncthreads();
    int rt = tid >> 3;          // t row 0..31
    int cc = (tid & 7) * 4;     // c 0..28
    ushort4_t o;
    o[0] = f2b(tile[cc + 0][rt]);
    o[1] = f2b(tile[cc + 1][rt]);
    o[2] = f2b(tile[cc + 2][rt]);
    o[3] = f2b(tile[cc + 3][rt]);
    *(ushort4_t*)&xT[((size_t)b * 2048 + t0 + rt) * 256 + c0 + cc] = o;
}

// ---------------------------------------------------------------------------
// GEMM: C[M][N] = A[M][K] @ Bw[N][K]^T + bias1 (+bias2 if col<bias2_lim), bf16 out
// 64x64 tile, 4 waves, MFMA 16x16x32 bf16
// ---------------------------------------------------------------------------
template<int RELU>
__global__ __launch_bounds__(256, 4) void gemm64(
    const unsigned short* __restrict__ A, const unsigned short* __restrict__ Bw,
    const float* __restrict__ bias1, const float* __restrict__ bias2, int bias2_lim,
    unsigned short* __restrict__ Cout, int K, int N)
{
    __shared__ unsigned short As[64][72];
    __shared__ unsigned short Bs[64][72];
    int m0 = blockIdx.x * 64, n0 = blockIdx.y * 64;
    int tid = threadIdx.x, lane = tid & 63, w = tid >> 6;
    int l15 = lane & 15, kq = lane >> 4;
    int lr = tid >> 2, lc = (tid & 3) * 16;
    f32x4 acc[4];
#pragma unroll
    for (int n = 0; n < 4; ++n) acc[n] = (f32x4){0.f, 0.f, 0.f, 0.f};

    for (int kt = 0; kt < K; kt += 64){
        short8 a0 = *(const short8*)&A[(size_t)(m0 + lr) * K + kt + lc];
        short8 a1 = *(const short8*)&A[(size_t)(m0 + lr) * K + kt + lc + 8];
        short8 b0 = *(const short8*)&Bw[(size_t)(n0 + lr) * K + kt + lc];
        short8 b1 = *(const short8*)&Bw[(size_t)(n0 + lr) * K + kt + lc + 8];
        __syncthreads();
        *(short8*)&As[lr][lc]     = a0;
        *(short8*)&As[lr][lc + 8] = a1;
        *(short8*)&Bs[lr][lc]     = b0;
        *(short8*)&Bs[lr][lc + 8] = b1;
        __syncthreads();
#pragma unroll
        for (int kc = 0; kc < 2; ++kc){
            short8 af = *(const short8*)&As[w * 16 + l15][kc * 32 + kq * 8];
#pragma unroll
            for (int n = 0; n < 4; ++n){
                short8 bfv = *(const short8*)&Bs[n * 16 + l15][kc * 32 + kq * 8];
                acc[n] = __builtin_amdgcn_mfma_f32_16x16x32_bf16(af, bfv, acc[n], 0, 0, 0);
            }
        }
    }
#pragma unroll
    for (int n = 0; n < 4; ++n){
        int col = n0 + n * 16 + l15;
        float bs = bias1 ? bias1[col] : 0.f;
        if (bias2 && col < bias2_lim) bs += bias2[col];
#pragma unroll
        for (int r = 0; r < 4; ++r){
            int row = m0 + w * 16 + kq * 4 + r;
            float v = acc[n][r] + bs;
            if (RELU) v = fmaxf(v, 0.f);
            Cout[(size_t)row * N + col] = f2b(v);
        }
    }
}

// ---------------------------------------------------------------------------
// Final FFN GEMM with f32 output written TRANSPOSED to (B,C,L):
// out[b][col][t] = A[row=b*2048+t] @ w2^T + b2
// ---------------------------------------------------------------------------
__global__ __launch_bounds__(256, 4) void gemm64_tr(
    const unsigned short* __restrict__ A, const unsigned short* __restrict__ Bw,
    const float* __restrict__ bias, float* __restrict__ Out, int K, int N)
{
    __shared__ unsigned short As[64][72];
    __shared__ unsigned short Bs[64][72];
    int m0 = blockIdx.x * 64, n0 = blockIdx.y * 64;
    int tid = threadIdx.x, lane = tid & 63, w = tid >> 6;
    int l15 = lane & 15, kq = lane >> 4;
    int lr = tid >> 2, lc = (tid & 3) * 16;
    f32x4 acc[4];
#pragma unroll
    for (int n = 0; n < 4; ++n) acc[n] = (f32x4){0.f, 0.f, 0.f, 0.f};

    for (int kt = 0; kt < K; kt += 64){
        short8 a0 = *(const short8*)&A[(size_t)(m0 + lr) * K + kt + lc];
        short8 a1 = *(const short8*)&A[(size_t)(m0 + lr) * K + kt + lc + 8];
        short8 b0 = *(const short8*)&Bw[(size_t)(n0 + lr) * K + kt + lc];
        short8 b1 = *(const short8*)&Bw[(size_t)(n0 + lr) * K + kt + lc + 8];
        __syncthreads();
        *(short8*)&As[lr][lc]     = a0;
        *(short8*)&As[lr][lc + 8] = a1;
        *(short8*)&Bs[lr][lc]     = b0;
        *(short8*)&Bs[lr][lc + 8] = b1;
        __syncthreads();
#pragma unroll
        for (int kc = 0; kc < 2; ++kc){
            short8 af = *(const short8*)&As[w * 16 + l15][kc * 32 + kq * 8];
#pragma unroll
            for (int n = 0; n < 4; ++n){
                short8 bfv = *(const short8*)&Bs[n * 16 + l15][kc * 32 + kq * 8];
                acc[n] = __builtin_amdgcn_mfma_f32_16x16x32_bf16(af, bfv, acc[n], 0, 0, 0);
            }
        }
    }
    int m_base = m0 + w * 16 + kq * 4;
    int bidx = m_base >> 11;
    int t0 = m_base & 2047;
#pragma unroll
    for (int n = 0; n < 4; ++n){
        int col = n0 + n * 16 + l15;
        float bs = bias[col];
        float4_t o = (float4_t){acc[n][0] + bs, acc[n][1] + bs, acc[n][2] + bs, acc[n][3] + bs};
        *(float4_t*)&Out[(size_t)bidx * 524288 + (size_t)col * 2048 + t0] = o;
    }
}

// ---------------------------------------------------------------------------
// GRU scan via v_dot2_f32_f16 with FULL on-chip weight residency:
//   pairs [0,88):   88 packed fp16 pairs pinned in VGPRs (78% incl. temps of
//                   the 170 budget — proven-safe zone; R7 showed pins stick)
//   pairs [88,128): 40 pairs per row staged in LDS (123 KB), layout
//                   [chunk j][tid] -> lane-contiguous ds_read_b128,
//                   ~480 cy/step of LDS BW overlapped with the VALU dot.
// No L2 traffic in the loop except the tiny gi stream (prefetched).
// 768 thr = 12 waves (3/SIMD). Lane owns W_hh row tid (gate g=tid>>8, col
// c=tid&255). h fp16 in LDS (uniform broadcast reads). 2 barriers/step.
// Step ~= 768 cy dot2 + ~250 gates/barriers.
// ---------------------------------------------------------------------------
__global__ __launch_bounds__(768, 3) void gru_scan_dot(
    const unsigned short* __restrict__ gi,
    const unsigned short* __restrict__ whh_f, const unsigned short* __restrict__ whh_b,
    const float* __restrict__ bhh_f, const float* __restrict__ bhh_b,
    unsigned short* __restrict__ outp, int out_stride, size_t out_dir_off)
{
    extern __shared__ __align__(16) char smem[];
    unsigned int* wlds = (unsigned int*)smem;                            // 10*768*4 dw = 122880 B
    unsigned int (*hlds)[128] = (unsigned int (*)[128])(smem + 122880);  // 2*128 dw = 1024 B
    float* gbuf = (float*)(smem + 123904);                               // 768 f32 = 3072 B
                                                                         // total 126976 B
    const int T = 2048;
    int b = blockIdx.x & 15, dir = blockIdx.x >> 4;
    const unsigned short* giP = gi + ((size_t)(dir * 16 + b)) * T * 768;
    const unsigned short* wP  = dir ? whh_b : whh_f;    // fp16 storage
    const float* bhP          = dir ? bhh_b : bhh_f;
    unsigned short* oP        = outp + out_dir_off * (size_t)dir;

    int tid = threadIdx.x;      // 0..767
    int g = tid >> 8;           // 0:r 1:z 2:n  (wave-uniform)
    int c = tid & 255;

    const uintx4* wrow = (const uintx4*)(wP + (size_t)tid * 256);

    // resident pairs [0,88) -> 88 pinned VGPRs
    unsigned int wres[88];
#pragma unroll
    for (int i = 0; i < 22; ++i){
        uintx4 v = wrow[i];
        wres[i * 4 + 0] = v[0];
        wres[i * 4 + 1] = v[1];
        wres[i * 4 + 2] = v[2];
        wres[i * 4 + 3] = v[3];
    }
#pragma unroll
    for (int i = 0; i < 88; ++i) asm volatile("" : "+v"(wres[i]));

    // LDS pairs [88,128): chunk j holds uintx4 #(22+j) of every row,
    // stored lane-contiguous for conflict-free b128 reads
    {
        uintx4* w4 = (uintx4*)wlds;
#pragma unroll
        for (int j = 0; j < 10; ++j)
            w4[j * 768 + tid] = wrow[22 + j];
    }

    float bhn = (g == 2) ? bhP[512 + c] : 0.f;

    if (tid < 128) hlds[0][tid] = 0;

    int tt0 = dir ? (T - 1) : 0;
    int tstep = dir ? -1 : 1;

    // gi for t=0
    unsigned short gcur = giP[(size_t)tt0 * 768 + tid];
    unsigned short gncur = 0;
    if (tid < 256) gncur = giP[(size_t)tt0 * 768 + 512 + c];
    __syncthreads();

    float hold = 0.f;
    int cur = 0, tt = tt0;
#pragma clang loop unroll(disable)
    for (int t = 0; t < T; ++t){
        int tn = (t + 1 < T) ? (tt + tstep) : tt;
        // prefetch next step's gi (hidden under dot phase)
        unsigned short gnx = giP[(size_t)tn * 768 + tid];
        unsigned short gnnx = 0;
        if (tid < 256) gnnx = giP[(size_t)tn * 768 + 512 + c];

        const uintx4* hlds4 = (const uintx4*)hlds[cur];
        const uintx4* w4 = (const uintx4*)wlds;

        float a0 = 0.f, a1 = 0.f, a2 = 0.f, a3 = 0.f;
        // resident dot: K dwords [0,88)
#pragma unroll
        for (int kk = 0; kk < 22; ++kk){
            uintx4 hv = hlds4[kk];
            a0 = dot2h(wres[kk * 4 + 0], hv[0], a0);
            a1 = dot2h(wres[kk * 4 + 1], hv[1], a1);
            a2 = dot2h(wres[kk * 4 + 2], hv[2], a2);
            a3 = dot2h(wres[kk * 4 + 3], hv[3], a3);
        }
        // LDS dot: K dwords [88,128)
#pragma unroll
        for (int j = 0; j < 10; ++j){
            uintx4 wv = w4[j * 768 + tid];
            uintx4 hv = hlds4[22 + j];
            a0 = dot2h(wv[0], hv[0], a0);
            a1 = dot2h(wv[1], hv[1], a1);
            a2 = dot2h(wv[2], hv[2], a2);
            a3 = dot2h(wv[3], hv[3], a3);
        }
        float a = (a0 + a1) + (a2 + a3);

        float val;
        if (g < 2) val = sigm(b2f(gcur) + a);   // r or z (sigmoid now)
        else       val = a + bhn;               // n partial (needs r later)
        gbuf[tid] = val;
        __syncthreads();                        // bar1: gates published

        int nxt = cur ^ 1;
        if (tid < 256){
            float rr = val;                     // own r (this lane computed it)
            float zz = gbuf[256 + c];
            float s  = gbuf[512 + c];
            float nn = tanh_(b2f(gncur) + rr * s);
            float hv = nn + zz * (hold - nn);
            hold = hv;
            ((unsigned short*)hlds[nxt])[c] = __builtin_bit_cast(unsigned short, (_Float16)hv);
            oP[(size_t)(b * T + tt) * out_stride + c] = f2b(hv);
        }
        __syncthreads();                        // bar2: h visible, gbuf free
        gcur = gnx; gncur = gnnx;
        tt += tstep;
        cur = nxt;
    }
}

// ---------------------------------------------------------------------------
// sum(fwd,bwd) + LayerNorm -> bf16 rows
// ---------------------------------------------------------------------------
__global__ __launch_bounds__(256, 4) void sum_ln(
    const unsigned short* __restrict__ h1, const float* __restrict__ g,
    const float* __restrict__ bb, unsigned short* __restrict__ vn)
{
    int row = blockIdx.x * 4 + (threadIdx.x >> 6);
    int lane = threadIdx.x & 63;
    ushort4_t fa = *(const ushort4_t*)&h1[(size_t)row * 256 + lane * 4];
    ushort4_t ba = *(const ushort4_t*)&h1[8388608 + (size_t)row * 256 + lane * 4];
    float v[4]; float s = 0.f, q = 0.f;
#pragma unroll
    for (int k = 0; k < 4; ++k){
        v[k] = b2f(fa[k]) + b2f(ba[k]);
        s += v[k]; q += v[k] * v[k];
    }
#pragma unroll
    for (int o = 32; o; o >>= 1){
        s += __shfl_xor(s, o);
        q += __shfl_xor(q, o);
    }
    float mu = s * (1.f / 256.f);
    float var = q * (1.f / 256.f) - mu * mu;
    float rs = rsqrtf(var + 1e-5f);
    float4_t gg = *(const float4_t*)&g[lane * 4];
    float4_t bv = *(const float4_t*)&bb[lane * 4];
    ushort4_t o4;
#pragma unroll
    for (int k = 0; k < 4; ++k) o4[k] = f2b((v[k] - mu) * rs * gg[k] + bv[k]);
    *(ushort4_t*)&vn[(size_t)row * 256 + lane * 4] = o4;
}

// ---------------------------------------------------------------------------
extern "C" void kernel_launch(void* const* d_in, const int* in_sizes, int n_in,
                              void* d_out, int out_size, void* d_ws, size_t ws_size,
                              hipStream_t stream)
{
    (void)in_sizes; (void)n_in; (void)out_size; (void)ws_size;
    const float* x = (const float*)d_in[0];

    char* ws = (char*)d_ws;
    unsigned short* xT   = (unsigned short*)(ws);                 // 16 MB   (later reused as vn)
    unsigned short* giA  = (unsigned short*)(ws + 16777216);      // 100.7MB (gi0 -> gi1 -> hid)
    unsigned short* h0   = (unsigned short*)(ws + 117440512);     // 33.6 MB (h0out -> h1out)
    unsigned short* wbuf = (unsigned short*)(ws + 150994944);     // 4.5 MB weights (bf16 / fp16)
    float* out = (float*)d_out;

    // allow >64KB dynamic LDS for the scan kernel (idempotent, host-side)
    (void)hipFuncSetAttribute((const void*)gru_scan_dot,
                              hipFuncAttributeMaxDynamicSharedMemorySize, 126976);

    // 1) cast weights (W_hh segs -> fp16 for the dot2 scan; others bf16)
    CastArgs ca;
    ca.s[0] = (const float*)d_in[1];   // w_ih0f
    ca.s[1] = (const float*)d_in[2];   // w_hh0f (fp16)
    ca.s[2] = (const float*)d_in[5];   // w_ih0b
    ca.s[3] = (const float*)d_in[6];   // w_hh0b (fp16)
    ca.s[4] = (const float*)d_in[9];   // w_ih1f
    ca.s[5] = (const float*)d_in[10];  // w_hh1f (fp16)
    ca.s[6] = (const float*)d_in[13];  // w_ih1b
    ca.s[7] = (const float*)d_in[14];  // w_hh1b (fp16)
    ca.s[8] = (const float*)d_in[19];  // w1
    ca.s[9] = (const float*)d_in[21];  // w2
    cast_w<<<dim3(192, 10), 256, 0, stream>>>(ca, wbuf);

    // 2) transpose x -> xT bf16
    transpose_x<<<dim3(64, 8, 16), 256, 0, stream>>>(x, xT);

    // 3) layer-0 input gates: gi0[dir] = xT @ w_ih0d^T + b_ih0d + b_hh0d(r,z)
    gemm64<0><<<dim3(512, 12), 256, 0, stream>>>(xT, wbuf + 0,
        (const float*)d_in[3], (const float*)d_in[4], 512, giA, 256, 768);
    gemm64<0><<<dim3(512, 12), 256, 0, stream>>>(xT, wbuf + 393216,
        (const float*)d_in[7], (const float*)d_in[8], 512, giA + (size_t)25165824, 256, 768);

    // 4) layer-0 scan -> h0 [32768][512] (fwd cols 0-255, bwd 256-511)
    gru_scan_dot<<<32, 768, 126976, stream>>>(giA, wbuf + 196608, wbuf + 589824,
        (const float*)d_in[4], (const float*)d_in[8], h0, 512, (size_t)256);

    // 5) layer-1 input gates from h0 (K=512)
    gemm64<0><<<dim3(512, 12), 256, 0, stream>>>(h0, wbuf + 786432,
        (const float*)d_in[11], (const float*)d_in[12], 512, giA, 512, 768);
    gemm64<0><<<dim3(512, 12), 256, 0, stream>>>(h0, wbuf + 1376256,
        (const float*)d_in[15], (const float*)d_in[16], 512, giA + (size_t)25165824, 512, 768);

    // 6) layer-1 scan -> h0 reused as h1out [2][32768][256]
    gru_scan_dot<<<32, 768, 126976, stream>>>(giA, wbuf + 1179648, wbuf + 1769472,
        (const float*)d_in[12], (const float*)d_in[16], h0, 256, (size_t)8388608);

    // 7) sum dirs + LayerNorm -> vn (reuse xT)
    sum_ln<<<8192, 256, 0, stream>>>(h0, (const float*)d_in[17], (const float*)d_in[18], xT);

    // 8) FFN1: relu(vn @ w1^T + b1) -> hid (reuse giA)
    gemm64<1><<<dim3(512, 8), 256, 0, stream>>>(xT, wbuf + 1966080,
        (const float*)d_in[20], nullptr, 0, giA, 256, 512);

    // 9) FFN2: hid @ w2^T + b2 -> d_out f32, transposed to (B,C,L)
    gemm64_tr<<<dim3(512, 4), 256, 0, stream>>>(giA, wbuf + 2097152,
        (const float*)d_in[22], out, 512, 256);
}